// Round 1
// baseline (297.633 us; speedup 1.0000x reference)
//
#include <hip/hip_runtime.h>

typedef __bf16 bf16;
typedef __bf16 bf16x8 __attribute__((ext_vector_type(8)));
typedef __bf16 bf16x4 __attribute__((ext_vector_type(4)));
typedef float  f32x4  __attribute__((ext_vector_type(4)));

#define AS1U(p) ((const __attribute__((address_space(1))) unsigned int*)(p))
#define AS3U(p) ((__attribute__((address_space(3))) unsigned int*)(p))

// ---------------- transpose + cast fp32 -> bf16 (W[k][n] -> WT[n][k]) -------
__global__ void transpose_cast_kernel(const float* __restrict__ W,
                                      bf16* __restrict__ WT, int dim) {
    __shared__ float tile[32][33];
    const int bj = blockIdx.x, bi = blockIdx.y;
    const int tx = threadIdx.x, ty = threadIdx.y;  // 32 x 8
#pragma unroll
    for (int i = 0; i < 4; i++) {
        tile[ty + i * 8][tx] = W[(size_t)(bi * 32 + ty + i * 8) * dim + bj * 32 + tx];
    }
    __syncthreads();
#pragma unroll
    for (int i = 0; i < 4; i++) {
        WT[(size_t)(bj * 32 + ty + i * 8) * dim + bi * 32 + tx] =
            (bf16)tile[tx][ty + i * 8];
    }
}

// ---------------- LayerNorm over 1024, fp32 in -> bf16 out ------------------
__global__ void layernorm_kernel(const float* __restrict__ x,
                                 const float* __restrict__ gamma,
                                 const float* __restrict__ beta,
                                 bf16* __restrict__ h) {
    const int row = blockIdx.x;
    const float* xr = x + (size_t)row * 1024;
    const int t = threadIdx.x;  // 256
    float4 v = ((const float4*)xr)[t];
    float s  = v.x + v.y + v.z + v.w;
    float s2 = v.x * v.x + v.y * v.y + v.z * v.z + v.w * v.w;
#pragma unroll
    for (int m = 1; m < 64; m <<= 1) {
        s  += __shfl_xor(s, m, 64);
        s2 += __shfl_xor(s2, m, 64);
    }
    __shared__ float ssum[4], ssum2[4];
    const int wid = t >> 6, lane = t & 63;
    if (lane == 0) { ssum[wid] = s; ssum2[wid] = s2; }
    __syncthreads();
    s  = ssum[0] + ssum[1] + ssum[2] + ssum[3];
    s2 = ssum2[0] + ssum2[1] + ssum2[2] + ssum2[3];
    const float mu  = s * (1.f / 1024.f);
    const float var = s2 * (1.f / 1024.f) - mu * mu;
    const float rs  = rsqrtf(var + 1e-5f);
    float4 g = ((const float4*)gamma)[t];
    float4 b = ((const float4*)beta)[t];
    bf16x4 o;
    o[0] = (bf16)((v.x - mu) * rs * g.x + b.x);
    o[1] = (bf16)((v.y - mu) * rs * g.y + b.y);
    o[2] = (bf16)((v.z - mu) * rs * g.z + b.z);
    o[3] = (bf16)((v.w - mu) * rs * g.w + b.w);
    ((bf16x4*)(h + (size_t)row * 1024))[t] = o;
}

// ---------------- GEMM: C[M][N] = A[M][K] @ BT[N][K]^T ----------------------
// 128x128 tile, BK=32, 4 waves (each 64x64), mfma 16x16x32 bf16.
// EPI 0: += bias(concat bq|bk|bv), relu for col>=2048, write bf16 (ldc=N)
// EPI 1: += bo + resid, write fp32
template <int EPI>
__global__ void gemm_kernel(const bf16* __restrict__ A, const bf16* __restrict__ BT,
                            int N, int K,
                            bf16* __restrict__ Cb,
                            const float* __restrict__ b0, const float* __restrict__ b1,
                            const float* __restrict__ b2,
                            float* __restrict__ Cf, const float* __restrict__ bo,
                            const float* __restrict__ resid) {
    __shared__ bf16 Asm[128][32];
    __shared__ bf16 Bsm[128][32];
    const int tid = threadIdx.x;
    const int lane = tid & 63, wave = tid >> 6;
    const int wr = wave >> 1, wc = wave & 1;
    const int tileN = blockIdx.x * 128, tileM = blockIdx.y * 128;
    const int row16 = lane & 15, g = lane >> 4;

    f32x4 acc[4][4] = {};

    for (int kt = 0; kt < K; kt += 32) {
#pragma unroll
        for (int i = 0; i < 2; i++) {  // A tile: 512 chunks of 16B
            int c = tid + i * 256;
            int r = c >> 2, cb = (c & 3) * 16;
            const char* g_ = (const char*)(A + (size_t)(tileM + r) * K + kt) + cb;
            char* l_ = (char*)&Asm[0][0] + c * 16;
            __builtin_amdgcn_global_load_lds(AS1U(g_), AS3U(l_), 16, 0, 0);
        }
#pragma unroll
        for (int i = 0; i < 2; i++) {  // B tile
            int c = tid + i * 256;
            int r = c >> 2, cb = (c & 3) * 16;
            const char* g_ = (const char*)(BT + (size_t)(tileN + r) * K + kt) + cb;
            char* l_ = (char*)&Bsm[0][0] + c * 16;
            __builtin_amdgcn_global_load_lds(AS1U(g_), AS3U(l_), 16, 0, 0);
        }
        __syncthreads();
        bf16x8 af[4], bfr[4];
#pragma unroll
        for (int m = 0; m < 4; m++)
            af[m] = *(const bf16x8*)&Asm[wr * 64 + m * 16 + row16][g * 8];
#pragma unroll
        for (int n = 0; n < 4; n++)
            bfr[n] = *(const bf16x8*)&Bsm[wc * 64 + n * 16 + row16][g * 8];
#pragma unroll
        for (int m = 0; m < 4; m++)
#pragma unroll
            for (int n = 0; n < 4; n++)
                acc[m][n] = __builtin_amdgcn_mfma_f32_16x16x32_bf16(af[m], bfr[n],
                                                                   acc[m][n], 0, 0, 0);
        __syncthreads();
    }
#pragma unroll
    for (int m = 0; m < 4; m++) {
        const int row = tileM + wr * 64 + m * 16 + g * 4;
#pragma unroll
        for (int n = 0; n < 4; n++) {
            const int col = tileN + wc * 64 + n * 16 + row16;
#pragma unroll
            for (int j = 0; j < 4; j++) {
                float v = acc[m][n][j];
                const int r = row + j;
                if (EPI == 0) {
                    float bias = col < 1024 ? b0[col]
                                 : col < 2048 ? b1[col - 1024] : b2[col - 2048];
                    v += bias;
                    if (col >= 2048) v = fmaxf(v, 0.f);
                    Cb[(size_t)r * N + col] = (bf16)v;
                } else {
                    v += bo[col] + resid[(size_t)r * N + col];
                    Cf[(size_t)r * N + col] = v;
                }
            }
        }
    }
}

// ---------------- flash attention ------------------------------------------
// grid: (qtile=16, bh=32), 256 threads (4 waves), QT=128 (32 q-rows/wave), KT=32
__global__ void attn_kernel(const bf16* __restrict__ qkv, bf16* __restrict__ Obuf) {
    const int bh = blockIdx.y;
    const int b = bh >> 4, hh = bh & 15;
    const int qbase = blockIdx.x * 128;
    const int tid = threadIdx.x, lane = tid & 63, wave = tid >> 6;
    const int wrow = wave * 32;
    const int row16 = lane & 15, g = lane >> 4;

    __shared__ bf16 VT[64][40];   // [d][tok], padded rows (80B) for banks
    __shared__ bf16 Pl[128][40];  // [q][tok], padded

    const bf16* qptr = qkv + (size_t)b * 2048 * 3072 + hh * 64;
    const bf16* kptr = qptr + 1024;
    const bf16* vptr = qptr + 2048;

    bf16x8 qf[2][2];
#pragma unroll
    for (int m = 0; m < 2; m++)
#pragma unroll
        for (int kk = 0; kk < 2; kk++)
            qf[m][kk] = *(const bf16x8*)(qptr +
                (size_t)(qbase + wrow + m * 16 + row16) * 3072 + kk * 32 + g * 8);

    f32x4 accO[2][4] = {};
    float mrow[2][4], lrow[2][4];
#pragma unroll
    for (int m = 0; m < 2; m++)
#pragma unroll
        for (int j = 0; j < 4; j++) { mrow[m][j] = -1e30f; lrow[m][j] = 0.f; }

    const float scale = 0.125f;  // 1/sqrt(64)

    for (int kt = 0; kt < 2048; kt += 32) {
        // stage V tile transposed into LDS
        {
            const int tok = tid >> 3;
            const int d0 = (tid & 7) * 8;
            bf16x8 vv = *(const bf16x8*)(vptr + (size_t)(kt + tok) * 3072 + d0);
#pragma unroll
            for (int e = 0; e < 8; e++) VT[d0 + e][tok] = vv[e];
        }
        // S = Q @ K^T (this tile)
        f32x4 accS[2][2] = {};
        bf16x8 kf[2][2];
#pragma unroll
        for (int n = 0; n < 2; n++)
#pragma unroll
            for (int kk = 0; kk < 2; kk++)
                kf[n][kk] = *(const bf16x8*)(kptr +
                    (size_t)(kt + n * 16 + row16) * 3072 + kk * 32 + g * 8);
#pragma unroll
        for (int kk = 0; kk < 2; kk++)
#pragma unroll
            for (int m = 0; m < 2; m++)
#pragma unroll
                for (int n = 0; n < 2; n++)
                    accS[m][n] = __builtin_amdgcn_mfma_f32_16x16x32_bf16(
                        qf[m][kk], kf[n][kk], accS[m][n], 0, 0, 0);
        // online softmax + write P to LDS
#pragma unroll
        for (int m = 0; m < 2; m++) {
#pragma unroll
            for (int j = 0; j < 4; j++) {
                float v0 = accS[m][0][j] * scale, v1 = accS[m][1][j] * scale;
                float t = fmaxf(v0, v1);
                t = fmaxf(t, __shfl_xor(t, 1));
                t = fmaxf(t, __shfl_xor(t, 2));
                t = fmaxf(t, __shfl_xor(t, 4));
                t = fmaxf(t, __shfl_xor(t, 8));
                const float mnew = fmaxf(mrow[m][j], t);
                const float p0 = __expf(v0 - mnew), p1 = __expf(v1 - mnew);
                float rs = p0 + p1;
                rs += __shfl_xor(rs, 1);
                rs += __shfl_xor(rs, 2);
                rs += __shfl_xor(rs, 4);
                rs += __shfl_xor(rs, 8);
                const float alpha = __expf(mrow[m][j] - mnew);
                lrow[m][j] = lrow[m][j] * alpha + rs;
                mrow[m][j] = mnew;
#pragma unroll
                for (int n = 0; n < 4; n++) accO[m][n][j] *= alpha;
                const int prow = wrow + m * 16 + g * 4 + j;
                Pl[prow][row16] = (bf16)p0;
                Pl[prow][16 + row16] = (bf16)p1;
            }
        }
        __syncthreads();
        // O += P @ V
        bf16x8 pf[2], vf[4];
#pragma unroll
        for (int m = 0; m < 2; m++)
            pf[m] = *(const bf16x8*)&Pl[wrow + m * 16 + row16][g * 8];
#pragma unroll
        for (int n = 0; n < 4; n++)
            vf[n] = *(const bf16x8*)&VT[n * 16 + row16][g * 8];
#pragma unroll
        for (int m = 0; m < 2; m++)
#pragma unroll
            for (int n = 0; n < 4; n++)
                accO[m][n] = __builtin_amdgcn_mfma_f32_16x16x32_bf16(
                    pf[m], vf[n], accO[m][n], 0, 0, 0);
        __syncthreads();
    }
    // epilogue: O /= l, store [b][h][t][d] bf16 (== "merged" layout)
    bf16* obase = Obuf + (size_t)(b * 16 + hh) * 2048 * 64;
#pragma unroll
    for (int m = 0; m < 2; m++) {
#pragma unroll
        for (int j = 0; j < 4; j++) {
            const int trow = qbase + wrow + m * 16 + g * 4 + j;
            const float inv = 1.f / lrow[m][j];
#pragma unroll
            for (int n = 0; n < 4; n++)
                obase[(size_t)trow * 64 + n * 16 + row16] =
                    (bf16)(accO[m][n][j] * inv);
        }
    }
}

extern "C" void kernel_launch(void* const* d_in, const int* in_sizes, int n_in,
                              void* d_out, int out_size, void* d_ws, size_t ws_size,
                              hipStream_t stream) {
    const float* q     = (const float*)d_in[0];
    const float* gamma = (const float*)d_in[3];
    const float* beta  = (const float*)d_in[4];
    const float* Wq    = (const float*)d_in[5];
    const float* bq    = (const float*)d_in[6];
    const float* Wk    = (const float*)d_in[7];
    const float* bk    = (const float*)d_in[8];
    const float* Wv    = (const float*)d_in[9];
    const float* bv    = (const float*)d_in[10];
    const float* Wo    = (const float*)d_in[11];
    const float* bo    = (const float*)d_in[12];
    float* out = (float*)d_out;

    char* ws = (char*)d_ws;
    bf16* h     = (bf16*)(ws);                          // 8 MB
    bf16* WcatT = (bf16*)(ws + (8u << 20));             // 6 MB  [3072][1024]
    bf16* WoT   = (bf16*)(ws + (14u << 20));            // 2 MB  [1024][1024]
    bf16* qkv   = (bf16*)(ws + (16u << 20));            // 24 MB [4096][3072]
    bf16* Obuf  = (bf16*)(ws + (40u << 20));            // 8 MB  [B][H][T][64]

    const dim3 tb(32, 8);
    transpose_cast_kernel<<<dim3(32, 32), tb, 0, stream>>>(Wq, WcatT, 1024);
    transpose_cast_kernel<<<dim3(32, 32), tb, 0, stream>>>(Wk, WcatT + (size_t)1024 * 1024, 1024);
    transpose_cast_kernel<<<dim3(32, 32), tb, 0, stream>>>(Wv, WcatT + (size_t)2048 * 1024, 1024);
    transpose_cast_kernel<<<dim3(32, 32), tb, 0, stream>>>(Wo, WoT, 1024);

    layernorm_kernel<<<4096, 256, 0, stream>>>(q, gamma, beta, h);

    gemm_kernel<0><<<dim3(24, 32), 256, 0, stream>>>(h, WcatT, 3072, 1024,
                                                     qkv, bq, bk, bv,
                                                     nullptr, nullptr, nullptr);

    attn_kernel<<<dim3(16, 32), 256, 0, stream>>>(qkv, Obuf);

    gemm_kernel<1><<<dim3(8, 32), 256, 0, stream>>>(Obuf, WoT, 1024, 1024,
                                                    nullptr, nullptr, nullptr, nullptr,
                                                    out, bo, q);
}

// Round 3
// 167.578 us; speedup vs baseline: 1.7761x; 1.7761x over previous
//
#include <hip/hip_runtime.h>

typedef __bf16 bf16;
typedef __bf16 bf16x8 __attribute__((ext_vector_type(8)));
typedef __bf16 bf16x4 __attribute__((ext_vector_type(4)));
typedef float  f32x4  __attribute__((ext_vector_type(4)));
typedef unsigned int u32;
typedef u32 u32x4 __attribute__((ext_vector_type(4)));

#define AS1U(p) ((const __attribute__((address_space(1))) unsigned int*)(p))
#define AS3U(p) ((__attribute__((address_space(3))) unsigned int*)(p))

static __device__ __forceinline__ u32 pack2(float a, float b) {
    unsigned short ua = __builtin_bit_cast(unsigned short, (bf16)a);
    unsigned short ub = __builtin_bit_cast(unsigned short, (bf16)b);
    return (u32)ua | ((u32)ub << 16);
}

// ---------------- transpose + cast fp32 -> bf16 (W[k][n] -> WT[n][k]) -------
__global__ void transpose_cast_kernel(const float* __restrict__ W,
                                      bf16* __restrict__ WT, int dim) {
    __shared__ float tile[32][33];
    const int bj = blockIdx.x, bi = blockIdx.y;
    const int tx = threadIdx.x, ty = threadIdx.y;  // 32 x 8
#pragma unroll
    for (int i = 0; i < 4; i++) {
        tile[ty + i * 8][tx] = W[(size_t)(bi * 32 + ty + i * 8) * dim + bj * 32 + tx];
    }
    __syncthreads();
#pragma unroll
    for (int i = 0; i < 4; i++) {
        WT[(size_t)(bj * 32 + ty + i * 8) * dim + bi * 32 + tx] =
            (bf16)tile[tx][ty + i * 8];
    }
}

// ---------------- LayerNorm over 1024, fp32 in -> bf16 out ------------------
__global__ void layernorm_kernel(const float* __restrict__ x,
                                 const float* __restrict__ gamma,
                                 const float* __restrict__ beta,
                                 bf16* __restrict__ h) {
    const int row = blockIdx.x;
    const float* xr = x + (size_t)row * 1024;
    const int t = threadIdx.x;  // 256
    float4 v = ((const float4*)xr)[t];
    float s  = v.x + v.y + v.z + v.w;
    float s2 = v.x * v.x + v.y * v.y + v.z * v.z + v.w * v.w;
#pragma unroll
    for (int m = 1; m < 64; m <<= 1) {
        s  += __shfl_xor(s, m, 64);
        s2 += __shfl_xor(s2, m, 64);
    }
    __shared__ float ssum[4], ssum2[4];
    const int wid = t >> 6, lane = t & 63;
    if (lane == 0) { ssum[wid] = s; ssum2[wid] = s2; }
    __syncthreads();
    s  = ssum[0] + ssum[1] + ssum[2] + ssum[3];
    s2 = ssum2[0] + ssum2[1] + ssum2[2] + ssum2[3];
    const float mu  = s * (1.f / 1024.f);
    const float var = s2 * (1.f / 1024.f) - mu * mu;
    const float rs  = rsqrtf(var + 1e-5f);
    float4 g = ((const float4*)gamma)[t];
    float4 b = ((const float4*)beta)[t];
    bf16x4 o;
    o[0] = (bf16)((v.x - mu) * rs * g.x + b.x);
    o[1] = (bf16)((v.y - mu) * rs * g.y + b.y);
    o[2] = (bf16)((v.z - mu) * rs * g.z + b.z);
    o[3] = (bf16)((v.w - mu) * rs * g.w + b.w);
    ((bf16x4*)(h + (size_t)row * 1024))[t] = o;
}

// ---------------- GEMM: C[M][N] = A[M][K] @ BT[N][K]^T ----------------------
// 128x128 tile, BK=32, 4 waves (each 64x64), mfma 16x16x32 bf16.
// EPI 0: += bias; cols<2048 -> qkv (Q,K); cols>=2048 -> relu, write V^T to Vt
// EPI 1: += bo + resid, write fp32
template <int EPI>
__global__ void gemm_kernel(const bf16* __restrict__ A, const bf16* __restrict__ BT,
                            int N, int K,
                            bf16* __restrict__ Cb,
                            const float* __restrict__ b0, const float* __restrict__ b1,
                            const float* __restrict__ b2, bf16* __restrict__ Vt,
                            float* __restrict__ Cf, const float* __restrict__ bo,
                            const float* __restrict__ resid) {
    __shared__ bf16 Asm[128][32];
    __shared__ bf16 Bsm[128][32];
    const int tid = threadIdx.x;
    const int lane = tid & 63, wave = tid >> 6;
    const int wr = wave >> 1, wc = wave & 1;
    const int tileN = blockIdx.x * 128, tileM = blockIdx.y * 128;
    const int row16 = lane & 15, g = lane >> 4;

    f32x4 acc[4][4] = {};

    for (int kt = 0; kt < K; kt += 32) {
#pragma unroll
        for (int i = 0; i < 2; i++) {  // A tile: 512 chunks of 16B
            int c = tid + i * 256;
            int r = c >> 2, cb = (c & 3) * 16;
            const char* g_ = (const char*)(A + (size_t)(tileM + r) * K + kt) + cb;
            char* l_ = (char*)&Asm[0][0] + c * 16;
            __builtin_amdgcn_global_load_lds(AS1U(g_), AS3U(l_), 16, 0, 0);
        }
#pragma unroll
        for (int i = 0; i < 2; i++) {  // B tile
            int c = tid + i * 256;
            int r = c >> 2, cb = (c & 3) * 16;
            const char* g_ = (const char*)(BT + (size_t)(tileN + r) * K + kt) + cb;
            char* l_ = (char*)&Bsm[0][0] + c * 16;
            __builtin_amdgcn_global_load_lds(AS1U(g_), AS3U(l_), 16, 0, 0);
        }
        __syncthreads();
        bf16x8 af[4], bfr[4];
#pragma unroll
        for (int m = 0; m < 4; m++)
            af[m] = *(const bf16x8*)&Asm[wr * 64 + m * 16 + row16][g * 8];
#pragma unroll
        for (int n = 0; n < 4; n++)
            bfr[n] = *(const bf16x8*)&Bsm[wc * 64 + n * 16 + row16][g * 8];
#pragma unroll
        for (int m = 0; m < 4; m++)
#pragma unroll
            for (int n = 0; n < 4; n++)
                acc[m][n] = __builtin_amdgcn_mfma_f32_16x16x32_bf16(af[m], bfr[n],
                                                                   acc[m][n], 0, 0, 0);
        __syncthreads();
    }
#pragma unroll
    for (int m = 0; m < 4; m++) {
        const int row = tileM + wr * 64 + m * 16 + g * 4;
#pragma unroll
        for (int n = 0; n < 4; n++) {
            const int col = tileN + wc * 64 + n * 16 + row16;
            if (EPI == 0 && col >= 2048) {
                // V path: relu, write transposed Vt[b][h][d][t] as bf16x4 over t
                const int d = col - 2048;
                const float bias = b2[d];
                bf16x4 pk;
#pragma unroll
                for (int j = 0; j < 4; j++) {
                    float v = acc[m][n][j] + bias;
                    pk[j] = (bf16)fmaxf(v, 0.f);
                }
                const int bb = row >> 11, tt = row & 2047;
                const int hh = d >> 6, dd = d & 63;
                *(bf16x4*)&Vt[(((size_t)bb * 16 + hh) * 64 + dd) * 2048 + tt] = pk;
            } else {
#pragma unroll
                for (int j = 0; j < 4; j++) {
                    float v = acc[m][n][j];
                    const int r = row + j;
                    if (EPI == 0) {
                        v += col < 1024 ? b0[col] : b1[col - 1024];
                        Cb[(size_t)r * N + col] = (bf16)v;
                    } else {
                        v += bo[col] + resid[(size_t)r * N + col];
                        Cf[(size_t)r * N + col] = v;
                    }
                }
            }
        }
    }
}

// ---------------- flash attention, swapped-QK^T, in-register P --------------
// grid 512 blocks (XCD-grouped), 512 threads = 8 waves, QT=128 (16 q/wave), KT=64
__global__ __launch_bounds__(512, 4)
void attn_kernel(const bf16* __restrict__ qkv, const bf16* __restrict__ Vt,
                 bf16* __restrict__ Obuf) {
    const int bid = blockIdx.x;
    const int swz = (bid & 7) * 64 + (bid >> 3);  // same bh contiguous per XCD
    const int bh = swz >> 4, qt = swz & 15;
    const int b = bh >> 4, h = bh & 15;
    const int qbase = qt * 128;
    const int tid = threadIdx.x;
    const int lane = tid & 63, wv = tid >> 6;
    const int row16 = lane & 15, g = lane >> 4;

    __shared__ bf16 Kl[2][64][64];
    __shared__ bf16 Vl[2][64][64];

    // Q frags (B-layout: lane holds q=row16 of this wave, d=kk*32+g*8+e), loop-invariant
    const bf16* qrow = qkv + (size_t)(b * 2048 + qbase + wv * 16 + row16) * 3072 + h * 64;
    const bf16x8 qf0 = *(const bf16x8*)(qrow + g * 8);
    const bf16x8 qf1 = *(const bf16x8*)(qrow + 32 + g * 8);

    // staging: thread t stages 16B of K and 16B of V, pre-swizzled source
    const char* kgbase = (const char*)(qkv + (size_t)b * 2048 * 3072 + 1024 + h * 64);
    const char* vgbase = (const char*)(Vt + (size_t)bh * 64 * 2048);
    const int srow = tid >> 3;
    const int scol = ((tid & 7) * 16) ^ ((srow & 7) << 4);
    const char* kgp = kgbase + (size_t)srow * 6144 + scol;   // srow = token
    const char* vgp = vgbase + (size_t)srow * 4096 + scol;   // srow = d; scol = token bytes
    char* kld = (char*)&Kl[0][0][0] + tid * 16;
    char* vld = (char*)&Vl[0][0][0] + tid * 16;

    __builtin_amdgcn_global_load_lds(AS1U(kgp), AS3U(kld), 16, 0, 0);
    __builtin_amdgcn_global_load_lds(AS1U(vgp), AS3U(vld), 16, 0, 0);

    f32x4 accO[4] = {};
    float m_r = -3.0e38f, l_r = 0.f;
    const float SC = 0.18033688011112042f;  // 0.125 * log2(e)

    // swizzled per-lane read offsets: row = n*16+row16, byte = row*128 + cx
    const int swx = (row16 & 7) << 4;
    const int cx0 = (g * 16) ^ swx;
    const int cx1 = (64 + g * 16) ^ swx;
    const int rbase = row16 * 128;
    // bpermute source byte-addrs for P redistribution
    const int srcA = (row16 + ((g & 1) << 5)) << 2;
    const int srcB = srcA + 64;
    const bool hi2 = g >= 2;
    const int jb = g << 2;  // alpha broadcast source lanes

    for (int t = 0; t < 32; ++t) {
        __syncthreads();  // buf[t&1] fully staged (compiler drains vmcnt)
        const int cur = t & 1;
        if (t < 31) {  // prefetch next tile; flies under compute
            const int nb = ((t + 1) & 1) * 8192;
            // K tile step: 64 tokens x 6144 B/token; V tile step: 64 tokens x 2 B
            __builtin_amdgcn_global_load_lds(AS1U(kgp + (size_t)(t + 1) * 64 * 6144),
                                             AS3U(kld + nb), 16, 0, 0);
            __builtin_amdgcn_global_load_lds(AS1U(vgp + (size_t)(t + 1) * 128),
                                             AS3U(vld + nb), 16, 0, 0);
        }
        const char* Kb = (const char*)&Kl[cur][0][0];
        const char* Vb = (const char*)&Vl[cur][0][0];

        // S^T = K @ Q^T : accT[n] rows k=n*16+g*4+j, col q=row16
        f32x4 accT[4];
#pragma unroll
        for (int n = 0; n < 4; n++) {
            const bf16x8 kf0 = *(const bf16x8*)(Kb + n * 2048 + rbase + cx0);
            const bf16x8 kf1 = *(const bf16x8*)(Kb + n * 2048 + rbase + cx1);
            f32x4 z = {};
            z = __builtin_amdgcn_mfma_f32_16x16x32_bf16(kf0, qf0, z, 0, 0, 0);
            accT[n] = __builtin_amdgcn_mfma_f32_16x16x32_bf16(kf1, qf1, z, 0, 0, 0);
        }

        // online softmax, fully in-lane (16 k-values) + 2 cross shuffles
        float sv[16];
        float mt = -3.0e38f;
#pragma unroll
        for (int n = 0; n < 4; n++)
#pragma unroll
            for (int j = 0; j < 4; j++) {
                const float x = accT[n][j] * SC;
                sv[n * 4 + j] = x;
                mt = fmaxf(mt, x);
            }
        mt = fmaxf(mt, __shfl_xor(mt, 16));
        mt = fmaxf(mt, __shfl_xor(mt, 32));
        const float mn = fmaxf(m_r, mt);
        float rsum = 0.f;
#pragma unroll
        for (int i = 0; i < 16; i++) {
            const float pv = exp2f(sv[i] - mn);
            sv[i] = pv;
            rsum += pv;
        }
        rsum += __shfl_xor(rsum, 16);
        rsum += __shfl_xor(rsum, 32);
        const float alpha = exp2f(m_r - mn);
        l_r = l_r * alpha + rsum;
        m_r = mn;

        // rescale accO rows (row q = g*4+j needs alpha from lane g*4+j)
        float aj[4];
#pragma unroll
        for (int j = 0; j < 4; j++) aj[j] = __shfl(alpha, jb + j);
#pragma unroll
        for (int n = 0; n < 4; n++)
#pragma unroll
            for (int j = 0; j < 4; j++) accO[n][j] *= aj[j];

        // pack P to bf16 pairs
        u32 pk01[4], pk23[4];
#pragma unroll
        for (int n = 0; n < 4; n++) {
            pk01[n] = pack2(sv[n * 4 + 0], sv[n * 4 + 1]);
            pk23[n] = pack2(sv[n * 4 + 2], sv[n * 4 + 3]);
        }

        // PV: build A-frag of P via bpermute, accumulate O
#pragma unroll
        for (int kk = 0; kk < 2; kk++) {
            const int n0 = kk * 2;
            const int w0a = __builtin_amdgcn_ds_bpermute(srcA, (int)pk01[n0]);
            const int w0b = __builtin_amdgcn_ds_bpermute(srcA, (int)pk01[n0 + 1]);
            const int w1a = __builtin_amdgcn_ds_bpermute(srcA, (int)pk23[n0]);
            const int w1b = __builtin_amdgcn_ds_bpermute(srcA, (int)pk23[n0 + 1]);
            const int w2a = __builtin_amdgcn_ds_bpermute(srcB, (int)pk01[n0]);
            const int w2b = __builtin_amdgcn_ds_bpermute(srcB, (int)pk01[n0 + 1]);
            const int w3a = __builtin_amdgcn_ds_bpermute(srcB, (int)pk23[n0]);
            const int w3b = __builtin_amdgcn_ds_bpermute(srcB, (int)pk23[n0 + 1]);
            u32x4 ww;
            ww[0] = (u32)(hi2 ? w0b : w0a);
            ww[1] = (u32)(hi2 ? w1b : w1a);
            ww[2] = (u32)(hi2 ? w2b : w2a);
            ww[3] = (u32)(hi2 ? w3b : w3a);
            const bf16x8 af = __builtin_bit_cast(bf16x8, ww);
            const int cx = kk ? cx1 : cx0;
#pragma unroll
            for (int n = 0; n < 4; n++) {
                const bf16x8 vf = *(const bf16x8*)(Vb + n * 2048 + rbase + cx);
                accO[n] = __builtin_amdgcn_mfma_f32_16x16x32_bf16(af, vf, accO[n], 0, 0, 0);
            }
        }
    }

    // epilogue: O /= l, store [b][h][t][d] bf16 (== "merged" layout)
    const float linv = 1.f / l_r;
    float li[4];
#pragma unroll
    for (int j = 0; j < 4; j++) li[j] = __shfl(linv, jb + j);
    bf16* ob = Obuf + ((size_t)bh * 2048 + qbase + wv * 16) * 64;
#pragma unroll
    for (int n = 0; n < 4; n++)
#pragma unroll
        for (int j = 0; j < 4; j++)
            ob[(size_t)(g * 4 + j) * 64 + n * 16 + row16] = (bf16)(accO[n][j] * li[j]);
}

extern "C" void kernel_launch(void* const* d_in, const int* in_sizes, int n_in,
                              void* d_out, int out_size, void* d_ws, size_t ws_size,
                              hipStream_t stream) {
    const float* q     = (const float*)d_in[0];
    const float* gamma = (const float*)d_in[3];
    const float* beta  = (const float*)d_in[4];
    const float* Wq    = (const float*)d_in[5];
    const float* bq    = (const float*)d_in[6];
    const float* Wk    = (const float*)d_in[7];
    const float* bk    = (const float*)d_in[8];
    const float* Wv    = (const float*)d_in[9];
    const float* bv    = (const float*)d_in[10];
    const float* Wo    = (const float*)d_in[11];
    const float* bo    = (const float*)d_in[12];
    float* out = (float*)d_out;

    char* ws = (char*)d_ws;
    bf16* h     = (bf16*)(ws);                          // 8 MB
    bf16* WcatT = (bf16*)(ws + (8u << 20));             // 6 MB  [3072][1024]
    bf16* WoT   = (bf16*)(ws + (14u << 20));            // 2 MB  [1024][1024]
    bf16* qkv   = (bf16*)(ws + (16u << 20));            // 24 MB [4096][3072] (Q,K used)
    bf16* Obuf  = (bf16*)(ws + (40u << 20));            // 8 MB  [B][H][T][64]
    bf16* Vtb   = (bf16*)(ws + (48u << 20));            // 8 MB  [B][H][64][T]

    const dim3 tb(32, 8);
    transpose_cast_kernel<<<dim3(32, 32), tb, 0, stream>>>(Wq, WcatT, 1024);
    transpose_cast_kernel<<<dim3(32, 32), tb, 0, stream>>>(Wk, WcatT + (size_t)1024 * 1024, 1024);
    transpose_cast_kernel<<<dim3(32, 32), tb, 0, stream>>>(Wv, WcatT + (size_t)2048 * 1024, 1024);
    transpose_cast_kernel<<<dim3(32, 32), tb, 0, stream>>>(Wo, WoT, 1024);

    layernorm_kernel<<<4096, 256, 0, stream>>>(q, gamma, beta, h);

    gemm_kernel<0><<<dim3(24, 32), 256, 0, stream>>>(h, WcatT, 3072, 1024,
                                                     qkv, bq, bk, bv, Vtb,
                                                     nullptr, nullptr, nullptr);

    attn_kernel<<<512, 512, 0, stream>>>(qkv, Vtb, Obuf);

    gemm_kernel<1><<<dim3(8, 32), 256, 0, stream>>>(Obuf, WoT, 1024, 1024,
                                                    nullptr, nullptr, nullptr, nullptr, nullptr,
                                                    out, bo, q);
}

// Round 4
// 154.877 us; speedup vs baseline: 1.9217x; 1.0820x over previous
//
#include <hip/hip_runtime.h>

typedef __bf16 bf16;
typedef __bf16 bf16x8 __attribute__((ext_vector_type(8)));
typedef __bf16 bf16x4 __attribute__((ext_vector_type(4)));
typedef float  f32x4  __attribute__((ext_vector_type(4)));
typedef unsigned int u32;
typedef u32 u32x4 __attribute__((ext_vector_type(4)));

#define AS1U(p) ((const __attribute__((address_space(1))) unsigned int*)(p))
#define AS3U(p) ((__attribute__((address_space(3))) unsigned int*)(p))

static __device__ __forceinline__ u32 pack2(float a, float b) {
    unsigned short ua = __builtin_bit_cast(unsigned short, (bf16)a);
    unsigned short ub = __builtin_bit_cast(unsigned short, (bf16)b);
    return (u32)ua | ((u32)ub << 16);
}

// ---------------- 4x transpose + cast fp32 -> bf16 (one launch) -------------
__global__ void transpose_cast4_kernel(const float* __restrict__ W0, const float* __restrict__ W1,
                                       const float* __restrict__ W2, const float* __restrict__ W3,
                                       bf16* __restrict__ D0, bf16* __restrict__ D1,
                                       bf16* __restrict__ D2, bf16* __restrict__ D3) {
    __shared__ float tile[32][33];
    const float* W; bf16* D;
    switch (blockIdx.z) {
        case 0: W = W0; D = D0; break;
        case 1: W = W1; D = D1; break;
        case 2: W = W2; D = D2; break;
        default: W = W3; D = D3; break;
    }
    const int bj = blockIdx.x, bi = blockIdx.y;
    const int tx = threadIdx.x, ty = threadIdx.y;  // 32 x 8
#pragma unroll
    for (int i = 0; i < 4; i++) {
        tile[ty + i * 8][tx] = W[(size_t)(bi * 32 + ty + i * 8) * 1024 + bj * 32 + tx];
    }
    __syncthreads();
#pragma unroll
    for (int i = 0; i < 4; i++) {
        D[(size_t)(bj * 32 + ty + i * 8) * 1024 + bi * 32 + tx] =
            (bf16)tile[tx][ty + i * 8];
    }
}

// ---------------- LayerNorm over 1024, fp32 in -> bf16 out ------------------
__global__ void layernorm_kernel(const float* __restrict__ x,
                                 const float* __restrict__ gamma,
                                 const float* __restrict__ beta,
                                 bf16* __restrict__ h) {
    const int row = blockIdx.x;
    const float* xr = x + (size_t)row * 1024;
    const int t = threadIdx.x;  // 256
    float4 v = ((const float4*)xr)[t];
    float s  = v.x + v.y + v.z + v.w;
    float s2 = v.x * v.x + v.y * v.y + v.z * v.z + v.w * v.w;
#pragma unroll
    for (int m = 1; m < 64; m <<= 1) {
        s  += __shfl_xor(s, m, 64);
        s2 += __shfl_xor(s2, m, 64);
    }
    __shared__ float ssum[4], ssum2[4];
    const int wid = t >> 6, lane = t & 63;
    if (lane == 0) { ssum[wid] = s; ssum2[wid] = s2; }
    __syncthreads();
    s  = ssum[0] + ssum[1] + ssum[2] + ssum[3];
    s2 = ssum2[0] + ssum2[1] + ssum2[2] + ssum2[3];
    const float mu  = s * (1.f / 1024.f);
    const float var = s2 * (1.f / 1024.f) - mu * mu;
    const float rs  = rsqrtf(var + 1e-5f);
    float4 g = ((const float4*)gamma)[t];
    float4 b = ((const float4*)beta)[t];
    bf16x4 o;
    o[0] = (bf16)((v.x - mu) * rs * g.x + b.x);
    o[1] = (bf16)((v.y - mu) * rs * g.y + b.y);
    o[2] = (bf16)((v.z - mu) * rs * g.z + b.z);
    o[3] = (bf16)((v.w - mu) * rs * g.w + b.w);
    ((bf16x4*)(h + (size_t)row * 1024))[t] = o;
}

// ---------------- GEMM: C[M][N] = A[M][K] @ BT[N][K]^T ----------------------
// 128x128 tile, BK=32, 4 waves (each 64x64), mfma 16x16x32 bf16.
// EPI 0: += bias; col<1024: Q, pre-scaled by 0.125*log2(e); 1024..2047: K;
//        col>=2048: relu -> V^T into Vt
// EPI 1: += bo + resid, write fp32
template <int EPI>
__global__ void gemm_kernel(const bf16* __restrict__ A, const bf16* __restrict__ BT,
                            int N, int K,
                            bf16* __restrict__ Cb,
                            const float* __restrict__ b0, const float* __restrict__ b1,
                            const float* __restrict__ b2, bf16* __restrict__ Vt,
                            float* __restrict__ Cf, const float* __restrict__ bo,
                            const float* __restrict__ resid) {
    __shared__ bf16 Asm[128][32];
    __shared__ bf16 Bsm[128][32];
    const int tid = threadIdx.x;
    const int lane = tid & 63, wave = tid >> 6;
    const int wr = wave >> 1, wc = wave & 1;
    const int tileN = blockIdx.x * 128, tileM = blockIdx.y * 128;
    const int row16 = lane & 15, g = lane >> 4;

    f32x4 acc[4][4] = {};

    for (int kt = 0; kt < K; kt += 32) {
#pragma unroll
        for (int i = 0; i < 2; i++) {  // A tile: 512 chunks of 16B
            int c = tid + i * 256;
            int r = c >> 2, cb = (c & 3) * 16;
            const char* g_ = (const char*)(A + (size_t)(tileM + r) * K + kt) + cb;
            char* l_ = (char*)&Asm[0][0] + c * 16;
            __builtin_amdgcn_global_load_lds(AS1U(g_), AS3U(l_), 16, 0, 0);
        }
#pragma unroll
        for (int i = 0; i < 2; i++) {  // B tile
            int c = tid + i * 256;
            int r = c >> 2, cb = (c & 3) * 16;
            const char* g_ = (const char*)(BT + (size_t)(tileN + r) * K + kt) + cb;
            char* l_ = (char*)&Bsm[0][0] + c * 16;
            __builtin_amdgcn_global_load_lds(AS1U(g_), AS3U(l_), 16, 0, 0);
        }
        __syncthreads();
        bf16x8 af[4], bfr[4];
#pragma unroll
        for (int m = 0; m < 4; m++)
            af[m] = *(const bf16x8*)&Asm[wr * 64 + m * 16 + row16][g * 8];
#pragma unroll
        for (int n = 0; n < 4; n++)
            bfr[n] = *(const bf16x8*)&Bsm[wc * 64 + n * 16 + row16][g * 8];
#pragma unroll
        for (int m = 0; m < 4; m++)
#pragma unroll
            for (int n = 0; n < 4; n++)
                acc[m][n] = __builtin_amdgcn_mfma_f32_16x16x32_bf16(af[m], bfr[n],
                                                                   acc[m][n], 0, 0, 0);
        __syncthreads();
    }
#pragma unroll
    for (int m = 0; m < 4; m++) {
        const int row = tileM + wr * 64 + m * 16 + g * 4;
#pragma unroll
        for (int n = 0; n < 4; n++) {
            const int col = tileN + wc * 64 + n * 16 + row16;
            if (EPI == 0 && col >= 2048) {
                // V path: relu, write transposed Vt[b][h][d][t] as bf16x4 over t
                const int d = col - 2048;
                const float bias = b2[d];
                bf16x4 pk;
#pragma unroll
                for (int j = 0; j < 4; j++) {
                    float v = acc[m][n][j] + bias;
                    pk[j] = (bf16)fmaxf(v, 0.f);
                }
                const int bb = row >> 11, tt = row & 2047;
                const int hh = d >> 6, dd = d & 63;
                *(bf16x4*)&Vt[(((size_t)bb * 16 + hh) * 64 + dd) * 2048 + tt] = pk;
            } else {
#pragma unroll
                for (int j = 0; j < 4; j++) {
                    float v = acc[m][n][j];
                    const int r = row + j;
                    if (EPI == 0) {
                        if (col < 1024) {
                            // Q: fold in softmax scale 0.125*log2(e)
                            v = (v + b0[col]) * 0.18033688011112042f;
                        } else {
                            v += b1[col - 1024];
                        }
                        Cb[(size_t)r * N + col] = (bf16)v;
                    } else {
                        v += bo[col] + resid[(size_t)r * N + col];
                        Cf[(size_t)r * N + col] = v;
                    }
                }
            }
        }
    }
}

// ---------------- flash attention, swapped-QK^T, fixed-max softmax ----------
// grid 1024 blocks (XCD-grouped), 256 threads = 4 waves, QT=64 (16 q/wave), KT=64
// Q pre-scaled by 0.125*log2(e) in GEMM1 -> P = exp2(S), divide by l at end.
__global__ __launch_bounds__(256, 4)
void attn_kernel(const bf16* __restrict__ qkv, const bf16* __restrict__ Vt,
                 bf16* __restrict__ Obuf) {
    const int bid = blockIdx.x;
    const int swz = (bid & 7) * 128 + (bid >> 3);  // same bh contiguous per XCD
    const int bh = swz >> 5, qt = swz & 31;
    const int b = bh >> 4, h = bh & 15;
    const int qbase = qt * 64;
    const int tid = threadIdx.x;
    const int lane = tid & 63, wv = tid >> 6;
    const int row16 = lane & 15, g = lane >> 4;

    __shared__ bf16 Kl[2][64][64];
    __shared__ bf16 Vl[2][64][64];

    // Q frags (B-layout: lane holds q=row16 of this wave, d=kk*32+g*8+e)
    const bf16* qrow = qkv + (size_t)(b * 2048 + qbase + wv * 16 + row16) * 3072 + h * 64;
    const bf16x8 qf0 = *(const bf16x8*)(qrow + g * 8);
    const bf16x8 qf1 = *(const bf16x8*)(qrow + 32 + g * 8);

    // staging: 256 threads x 2 chunks of 16B for each of K and V, pre-swizzled src
    const char* kgbase = (const char*)(qkv + (size_t)b * 2048 * 3072 + 1024 + h * 64);
    const char* vgbase = (const char*)(Vt + (size_t)bh * 64 * 2048);
    const int c0 = tid, c1 = tid + 256;
    const int sr0 = c0 >> 3, sc0 = ((c0 & 7) * 16) ^ ((sr0 & 7) << 4);
    const int sr1 = c1 >> 3, sc1 = ((c1 & 7) * 16) ^ ((sr1 & 7) << 4);
    const char* kgp0 = kgbase + (size_t)sr0 * 6144 + sc0;   // row = token
    const char* kgp1 = kgbase + (size_t)sr1 * 6144 + sc1;
    const char* vgp0 = vgbase + (size_t)sr0 * 4096 + sc0;   // row = d; col = token bytes
    const char* vgp1 = vgbase + (size_t)sr1 * 4096 + sc1;
    char* kld0 = (char*)&Kl[0][0][0] + c0 * 16;
    char* kld1 = (char*)&Kl[0][0][0] + c1 * 16;
    char* vld0 = (char*)&Vl[0][0][0] + c0 * 16;
    char* vld1 = (char*)&Vl[0][0][0] + c1 * 16;

    __builtin_amdgcn_global_load_lds(AS1U(kgp0), AS3U(kld0), 16, 0, 0);
    __builtin_amdgcn_global_load_lds(AS1U(kgp1), AS3U(kld1), 16, 0, 0);
    __builtin_amdgcn_global_load_lds(AS1U(vgp0), AS3U(vld0), 16, 0, 0);
    __builtin_amdgcn_global_load_lds(AS1U(vgp1), AS3U(vld1), 16, 0, 0);

    f32x4 accO[4] = {};
    float l_r = 0.f;

    // swizzled per-lane read offsets: row = n*16+row16, byte = row*128 + cx
    const int swx = (row16 & 7) << 4;
    const int cx0 = (g * 16) ^ swx;
    const int cx1 = (64 + g * 16) ^ swx;
    const int rbase = row16 * 128;
    // bpermute source byte-addrs for P redistribution
    const int srcA = (row16 + ((g & 1) << 5)) << 2;
    const int srcB = srcA + 64;
    const bool hi2 = g >= 2;
    const int jb = g << 2;

    for (int t = 0; t < 32; ++t) {
        __syncthreads();  // buf[t&1] fully staged (compiler drains vmcnt)
        const int cur = t & 1;
        if (t < 31) {  // prefetch next tile; flies under compute
            const int nb = ((t + 1) & 1) * 8192;
            const size_t ko = (size_t)(t + 1) * 64 * 6144;  // 64 tokens fwd
            const size_t vo = (size_t)(t + 1) * 128;        // 64 tokens * 2B fwd
            __builtin_amdgcn_global_load_lds(AS1U(kgp0 + ko), AS3U(kld0 + nb), 16, 0, 0);
            __builtin_amdgcn_global_load_lds(AS1U(kgp1 + ko), AS3U(kld1 + nb), 16, 0, 0);
            __builtin_amdgcn_global_load_lds(AS1U(vgp0 + vo), AS3U(vld0 + nb), 16, 0, 0);
            __builtin_amdgcn_global_load_lds(AS1U(vgp1 + vo), AS3U(vld1 + nb), 16, 0, 0);
        }
        const char* Kb = (const char*)&Kl[cur][0][0];
        const char* Vb = (const char*)&Vl[cur][0][0];

        // S^T = K @ Q^T : accT[n] rows k=n*16+g*4+j, col q=row16
        f32x4 accT[4];
#pragma unroll
        for (int n = 0; n < 4; n++) {
            const bf16x8 kf0 = *(const bf16x8*)(Kb + n * 2048 + rbase + cx0);
            const bf16x8 kf1 = *(const bf16x8*)(Kb + n * 2048 + rbase + cx1);
            f32x4 z = {};
            z = __builtin_amdgcn_mfma_f32_16x16x32_bf16(kf0, qf0, z, 0, 0, 0);
            accT[n] = __builtin_amdgcn_mfma_f32_16x16x32_bf16(kf1, qf1, z, 0, 0, 0);
        }

        // fixed-max softmax: P = exp2(S) (Q pre-scaled), per-lane partial sum
        float sv[16];
        float rs0 = 0.f, rs1 = 0.f;
#pragma unroll
        for (int n = 0; n < 4; n++)
#pragma unroll
            for (int j = 0; j < 4; j++) {
                const float pv = exp2f(accT[n][j]);
                sv[n * 4 + j] = pv;
                if (n & 1) rs1 += pv; else rs0 += pv;
            }
        l_r += rs0 + rs1;

        // pack P to bf16 pairs
        u32 pk01[4], pk23[4];
#pragma unroll
        for (int n = 0; n < 4; n++) {
            pk01[n] = pack2(sv[n * 4 + 0], sv[n * 4 + 1]);
            pk23[n] = pack2(sv[n * 4 + 2], sv[n * 4 + 3]);
        }

        // PV: build A-frag of P via bpermute, accumulate O
#pragma unroll
        for (int kk = 0; kk < 2; kk++) {
            const int n0 = kk * 2;
            const int w0a = __builtin_amdgcn_ds_bpermute(srcA, (int)pk01[n0]);
            const int w0b = __builtin_amdgcn_ds_bpermute(srcA, (int)pk01[n0 + 1]);
            const int w1a = __builtin_amdgcn_ds_bpermute(srcA, (int)pk23[n0]);
            const int w1b = __builtin_amdgcn_ds_bpermute(srcA, (int)pk23[n0 + 1]);
            const int w2a = __builtin_amdgcn_ds_bpermute(srcB, (int)pk01[n0]);
            const int w2b = __builtin_amdgcn_ds_bpermute(srcB, (int)pk01[n0 + 1]);
            const int w3a = __builtin_amdgcn_ds_bpermute(srcB, (int)pk23[n0]);
            const int w3b = __builtin_amdgcn_ds_bpermute(srcB, (int)pk23[n0 + 1]);
            u32x4 ww;
            ww[0] = (u32)(hi2 ? w0b : w0a);
            ww[1] = (u32)(hi2 ? w1b : w1a);
            ww[2] = (u32)(hi2 ? w2b : w2a);
            ww[3] = (u32)(hi2 ? w3b : w3a);
            const bf16x8 af = __builtin_bit_cast(bf16x8, ww);
            const int cx = kk ? cx1 : cx0;
#pragma unroll
            for (int n = 0; n < 4; n++) {
                const bf16x8 vf = *(const bf16x8*)(Vb + n * 2048 + rbase + cx);
                accO[n] = __builtin_amdgcn_mfma_f32_16x16x32_bf16(af, vf, accO[n], 0, 0, 0);
            }
        }
    }

    // epilogue: reduce l across the 4 lane-groups, O /= l,
    // store [b][h][t][d] bf16 (== "merged" layout)
    l_r += __shfl_xor(l_r, 16);
    l_r += __shfl_xor(l_r, 32);
    const float linv = 1.f / l_r;
    float li[4];
#pragma unroll
    for (int j = 0; j < 4; j++) li[j] = __shfl(linv, jb + j);
    bf16* ob = Obuf + ((size_t)bh * 2048 + qbase + wv * 16) * 64;
#pragma unroll
    for (int n = 0; n < 4; n++)
#pragma unroll
        for (int j = 0; j < 4; j++)
            ob[(size_t)(g * 4 + j) * 64 + n * 16 + row16] = (bf16)(accO[n][j] * li[j]);
}

extern "C" void kernel_launch(void* const* d_in, const int* in_sizes, int n_in,
                              void* d_out, int out_size, void* d_ws, size_t ws_size,
                              hipStream_t stream) {
    const float* q     = (const float*)d_in[0];
    const float* gamma = (const float*)d_in[3];
    const float* beta  = (const float*)d_in[4];
    const float* Wq    = (const float*)d_in[5];
    const float* bq    = (const float*)d_in[6];
    const float* Wk    = (const float*)d_in[7];
    const float* bk    = (const float*)d_in[8];
    const float* Wv    = (const float*)d_in[9];
    const float* bv    = (const float*)d_in[10];
    const float* Wo    = (const float*)d_in[11];
    const float* bo    = (const float*)d_in[12];
    float* out = (float*)d_out;

    char* ws = (char*)d_ws;
    bf16* h     = (bf16*)(ws);                          // 8 MB
    bf16* WcatT = (bf16*)(ws + (8u << 20));             // 6 MB  [3072][1024]
    bf16* WoT   = (bf16*)(ws + (14u << 20));            // 2 MB  [1024][1024]
    bf16* qkv   = (bf16*)(ws + (16u << 20));            // 24 MB [4096][3072] (Q,K used)
    bf16* Obuf  = (bf16*)(ws + (40u << 20));            // 8 MB  [B][H][T][64]
    bf16* Vtb   = (bf16*)(ws + (48u << 20));            // 8 MB  [B][H][64][T]

    transpose_cast4_kernel<<<dim3(32, 32, 4), dim3(32, 8), 0, stream>>>(
        Wq, Wk, Wv, Wo,
        WcatT, WcatT + (size_t)1024 * 1024, WcatT + (size_t)2048 * 1024, WoT);

    layernorm_kernel<<<4096, 256, 0, stream>>>(q, gamma, beta, h);

    gemm_kernel<0><<<dim3(24, 32), 256, 0, stream>>>(h, WcatT, 3072, 1024,
                                                     qkv, bq, bk, bv, Vtb,
                                                     nullptr, nullptr, nullptr);

    attn_kernel<<<1024, 256, 0, stream>>>(qkv, Vtb, Obuf);

    gemm_kernel<1><<<dim3(8, 32), 256, 0, stream>>>(Obuf, WoT, 1024, 1024,
                                                    nullptr, nullptr, nullptr, nullptr, nullptr,
                                                    out, bo, q);
}